// Round 2
// baseline (304.674 us; speedup 1.0000x reference)
//
#include <hip/hip_runtime.h>

// KalmanGain: B=262144, N=8, M=4, fp32. One thread per batch.
// Sigma = F Sp F^T + Q ; A = Sigma H^T ; S = H A + R ; KG = A inv(S).
// Register-economy restructure (round 2): F is never fully resident.
//   u = (H F)^T        (stream F rows, outer-product accumulate)
//   w = Sp u           (stream Sp rows)
//   A = F w            (stream F rows again -- 2nd pass served by LLC)
//   A += Q H^T         (stream Q rows)
//   S = H A + R ; KG = A inv(S)
// Peak live set ~104 floats -> target <=128 VGPR -> 4 waves/SIMD (vs 3 @160).
// Every streamed loop prefetches the next row so one load stays in flight.

__global__ __launch_bounds__(256, 4) void kalman_gain_kernel(
    const float* __restrict__ Fg, const float* __restrict__ Hg,
    const float* __restrict__ Spg, const float* __restrict__ Qg,
    const float* __restrict__ Rg, float* __restrict__ out, int nb)
{
    int b = blockIdx.x * blockDim.x + threadIdx.x;
    if (b >= nb) return;

    const float4* F4  = reinterpret_cast<const float4*>(Fg  + (size_t)b * 64);
    const float4* H4  = reinterpret_cast<const float4*>(Hg  + (size_t)b * 32);
    const float4* Sp4 = reinterpret_cast<const float4*>(Spg + (size_t)b * 64);
    const float4* Q4  = reinterpret_cast<const float4*>(Qg  + (size_t)b * 64);
    const float4* R4  = reinterpret_cast<const float4*>(Rg  + (size_t)b * 16);

    // ---- load H [4][8] ----
    float h[32];
    #pragma unroll
    for (int i = 0; i < 8; ++i) {
        float4 v = H4[i];
        h[4*i+0] = v.x; h[4*i+1] = v.y; h[4*i+2] = v.z; h[4*i+3] = v.w;
    }

    // ---- u = (H F)^T  [8][4]: u[k][j] = sum_r h[j][r] * f[r][k]  (stream F) ----
    float u[32];
    #pragma unroll
    for (int k = 0; k < 32; ++k) u[k] = 0.f;
    {
        float4 n0 = F4[0], n1 = F4[1];
        #pragma unroll
        for (int r = 0; r < 8; ++r) {
            float fr[8] = {n0.x,n0.y,n0.z,n0.w, n1.x,n1.y,n1.z,n1.w};
            if (r < 7) { n0 = F4[2*r+2]; n1 = F4[2*r+3]; }
            #pragma unroll
            for (int k = 0; k < 8; ++k)
                #pragma unroll
                for (int j = 0; j < 4; ++j)
                    u[k*4+j] += h[j*8+r] * fr[k];
        }
    }

    // ---- w = Sp @ u  [8][4]  (stream Sp rows; w row i depends only on Sp row i) ----
    float w[32];
    {
        float4 n0 = Sp4[0], n1 = Sp4[1];
        #pragma unroll
        for (int i = 0; i < 8; ++i) {
            float sp[8] = {n0.x,n0.y,n0.z,n0.w, n1.x,n1.y,n1.z,n1.w};
            if (i < 7) { n0 = Sp4[2*i+2]; n1 = Sp4[2*i+3]; }
            #pragma unroll
            for (int j = 0; j < 4; ++j) {
                float acc = 0.f;
                #pragma unroll
                for (int k = 0; k < 8; ++k)
                    acc += sp[k] * u[k*4+j];
                w[i*4+j] = acc;
            }
        }
    }
    // u dead from here.

    // ---- A = F @ w  [8][4]  (stream F rows, pass 2 -- LLC-resident) ----
    float A[32];
    {
        float4 n0 = F4[0], n1 = F4[1];
        #pragma unroll
        for (int i = 0; i < 8; ++i) {
            float fr[8] = {n0.x,n0.y,n0.z,n0.w, n1.x,n1.y,n1.z,n1.w};
            if (i < 7) { n0 = F4[2*i+2]; n1 = F4[2*i+3]; }
            #pragma unroll
            for (int j = 0; j < 4; ++j) {
                float acc = 0.f;
                #pragma unroll
                for (int k = 0; k < 8; ++k)
                    acc += fr[k] * w[k*4+j];
                A[i*4+j] = acc;
            }
        }
    }
    // w dead from here.

    // ---- A += Q @ H^T  (stream Q rows) ----
    {
        float4 n0 = Q4[0], n1 = Q4[1];
        #pragma unroll
        for (int i = 0; i < 8; ++i) {
            float q[8] = {n0.x,n0.y,n0.z,n0.w, n1.x,n1.y,n1.z,n1.w};
            if (i < 7) { n0 = Q4[2*i+2]; n1 = Q4[2*i+3]; }
            #pragma unroll
            for (int j = 0; j < 4; ++j) {
                float acc = 0.f;
                #pragma unroll
                for (int k = 0; k < 8; ++k)
                    acc += q[k] * h[j*8+k];
                A[i*4+j] += acc;
            }
        }
    }

    // ---- S = H @ A + R  [4][4] ----
    float s[16];
    #pragma unroll
    for (int i = 0; i < 4; ++i) {
        float4 v = R4[i];
        s[4*i+0] = v.x; s[4*i+1] = v.y; s[4*i+2] = v.z; s[4*i+3] = v.w;
    }
    #pragma unroll
    for (int p = 0; p < 4; ++p) {
        #pragma unroll
        for (int q = 0; q < 4; ++q) {
            float acc = 0.f;
            #pragma unroll
            for (int i = 0; i < 8; ++i)
                acc += h[p*8+i] * A[i*4+q];
            s[p*4+q] += acc;
        }
    }
    // h dead from here.

    // ---- invert S (4x4 SPD) via unrolled Gauss-Jordan, no pivoting ----
    float is[16] = {1.f,0.f,0.f,0.f, 0.f,1.f,0.f,0.f, 0.f,0.f,1.f,0.f, 0.f,0.f,0.f,1.f};
    #pragma unroll
    for (int c = 0; c < 4; ++c) {
        float pinv = 1.0f / s[c*4+c];
        #pragma unroll
        for (int k = 0; k < 4; ++k) { s[c*4+k] *= pinv; is[c*4+k] *= pinv; }
        #pragma unroll
        for (int r = 0; r < 4; ++r) {
            if (r != c) {
                float fac = s[r*4+c];
                #pragma unroll
                for (int k = 0; k < 4; ++k) {
                    s[r*4+k]  -= fac * s[c*4+k];
                    is[r*4+k] -= fac * is[c*4+k];
                }
            }
        }
    }

    // ---- KG = A @ inv(S)  [8][4], store ----
    float4* out4 = reinterpret_cast<float4*>(out + (size_t)b * 32);
    #pragma unroll
    for (int i = 0; i < 8; ++i) {
        float4 o;
        o.x = A[i*4+0]*is[0] + A[i*4+1]*is[4] + A[i*4+2]*is[8]  + A[i*4+3]*is[12];
        o.y = A[i*4+0]*is[1] + A[i*4+1]*is[5] + A[i*4+2]*is[9]  + A[i*4+3]*is[13];
        o.z = A[i*4+0]*is[2] + A[i*4+1]*is[6] + A[i*4+2]*is[10] + A[i*4+3]*is[14];
        o.w = A[i*4+0]*is[3] + A[i*4+1]*is[7] + A[i*4+2]*is[11] + A[i*4+3]*is[15];
        out4[i] = o;
    }
}

extern "C" void kernel_launch(void* const* d_in, const int* in_sizes, int n_in,
                              void* d_out, int out_size, void* d_ws, size_t ws_size,
                              hipStream_t stream) {
    const float* F  = (const float*)d_in[0];
    const float* H  = (const float*)d_in[1];
    const float* Sp = (const float*)d_in[2];
    const float* Q  = (const float*)d_in[3];
    const float* R  = (const float*)d_in[4];
    float* out = (float*)d_out;

    int nb = in_sizes[0] / 64;  // B = 262144
    int threads = 256;
    int blocks = (nb + threads - 1) / threads;
    kalman_gain_kernel<<<blocks, threads, 0, stream>>>(F, H, Sp, Q, R, out, nb);
}

// Round 3
// 77.274 us; speedup vs baseline: 3.9428x; 3.9428x over previous
//
#include <hip/hip_runtime.h>

// KalmanGain: B=262144, N=8, M=4, fp32.
// Round 3: TWO lanes per batch (lane pair via shfl_xor(...,1)).
// Each lane owns 4 of the 8 state rows. F is streamed (never fully resident).
//   u = (H F)^T      : own-row outer products, pair-summed via shfl
//   w = Sp u         : own Sp rows -> own w rows; partner half via shfl
//   A = F w + Q H^T  : own F/Q rows streamed -> own 4 rows of A
//   S = H A + R      : own-row partials, pair-summed via shfl
//   KG = A inv(S)    : inverse computed redundantly per lane; own 4 rows stored
// All array indices are compile-time constants; divergent half-selection is
// done on VALUES (cndmask), never on subscripts (avoids scratch).
// No launch_bounds min-wave forcing (round-2 spill lesson).

__global__ __launch_bounds__(256) void kalman_gain_kernel(
    const float* __restrict__ Fg, const float* __restrict__ Hg,
    const float* __restrict__ Spg, const float* __restrict__ Qg,
    const float* __restrict__ Rg, float* __restrict__ out, int nb)
{
    int t = blockIdx.x * blockDim.x + threadIdx.x;
    int b = t >> 1;          // batch
    int p = t & 1;           // half: 0 -> rows 0..3, 1 -> rows 4..7
    if (b >= nb) return;

    const float4* F4  = reinterpret_cast<const float4*>(Fg  + (size_t)b * 64);
    const float4* H4  = reinterpret_cast<const float4*>(Hg  + (size_t)b * 32);
    const float4* Sp4 = reinterpret_cast<const float4*>(Spg + (size_t)b * 64);
    const float4* Q4  = reinterpret_cast<const float4*>(Qg  + (size_t)b * 64);
    const float4* R4  = reinterpret_cast<const float4*>(Rg  + (size_t)b * 16);

    const int r0 = p * 4;    // first owned global row index

    // ---- load H [4][8] (full, both lanes) ----
    float h[32];
    #pragma unroll
    for (int i = 0; i < 8; ++i) {
        float4 v = H4[i];
        h[4*i+0] = v.x; h[4*i+1] = v.y; h[4*i+2] = v.z; h[4*i+3] = v.w;
    }

    // ---- hs[j][rl] = h[j][p*4+rl] : own-column slice of H (value select) ----
    float hs[16];
    #pragma unroll
    for (int j = 0; j < 4; ++j)
        #pragma unroll
        for (int rl = 0; rl < 4; ++rl)
            hs[j*4+rl] = p ? h[j*8+4+rl] : h[j*8+rl];

    // ---- u = (H F)^T [8][4]: own-row outer products, then pair-sum ----
    float u[32];
    #pragma unroll
    for (int x = 0; x < 32; ++x) u[x] = 0.f;
    #pragma unroll
    for (int rl = 0; rl < 4; ++rl) {
        float4 a0 = F4[(r0+rl)*2], a1 = F4[(r0+rl)*2+1];
        float fr[8] = {a0.x,a0.y,a0.z,a0.w, a1.x,a1.y,a1.z,a1.w};
        #pragma unroll
        for (int k = 0; k < 8; ++k)
            #pragma unroll
            for (int j = 0; j < 4; ++j)
                u[k*4+j] += hs[j*4+rl] * fr[k];
    }
    #pragma unroll
    for (int x = 0; x < 32; ++x) u[x] += __shfl_xor(u[x], 1, 64);

    // ---- w_own[il][j] = Sp(own row) . u(:,j) ----
    float wo[16];
    #pragma unroll
    for (int il = 0; il < 4; ++il) {
        float4 a0 = Sp4[(r0+il)*2], a1 = Sp4[(r0+il)*2+1];
        float sp[8] = {a0.x,a0.y,a0.z,a0.w, a1.x,a1.y,a1.z,a1.w};
        #pragma unroll
        for (int j = 0; j < 4; ++j) {
            float acc = 0.f;
            #pragma unroll
            for (int k = 0; k < 8; ++k)
                acc += sp[k] * u[k*4+j];
            wo[il*4+j] = acc;
        }
    }
    // u dead. Assemble w in GLOBAL row order (value cndmask, static indices).
    float wx[16];
    #pragma unroll
    for (int x = 0; x < 16; ++x) wx[x] = __shfl_xor(wo[x], 1, 64);
    float wg[32];
    #pragma unroll
    for (int x = 0; x < 16; ++x) {
        wg[x]      = p ? wx[x] : wo[x];   // global rows 0..3
        wg[16+x]   = p ? wo[x] : wx[x];   // global rows 4..7
    }

    // ---- A_own = F(own rows) @ wg   [4][4] (stream F pass 2) ----
    float A[16];
    #pragma unroll
    for (int il = 0; il < 4; ++il) {
        float4 a0 = F4[(r0+il)*2], a1 = F4[(r0+il)*2+1];
        float fr[8] = {a0.x,a0.y,a0.z,a0.w, a1.x,a1.y,a1.z,a1.w};
        #pragma unroll
        for (int j = 0; j < 4; ++j) {
            float acc = 0.f;
            #pragma unroll
            for (int k = 0; k < 8; ++k)
                acc += fr[k] * wg[k*4+j];
            A[il*4+j] = acc;
        }
    }

    // ---- A_own += Q(own rows) @ H^T ----
    #pragma unroll
    for (int il = 0; il < 4; ++il) {
        float4 a0 = Q4[(r0+il)*2], a1 = Q4[(r0+il)*2+1];
        float q[8] = {a0.x,a0.y,a0.z,a0.w, a1.x,a1.y,a1.z,a1.w};
        #pragma unroll
        for (int j = 0; j < 4; ++j) {
            float acc = 0.f;
            #pragma unroll
            for (int k = 0; k < 8; ++k)
                acc += q[k] * h[j*8+k];
            A[il*4+j] += acc;
        }
    }

    // ---- S = H A + R : own-row partials then pair-sum ----
    float s[16];
    #pragma unroll
    for (int pi = 0; pi < 4; ++pi)
        #pragma unroll
        for (int q = 0; q < 4; ++q) {
            float acc = 0.f;
            #pragma unroll
            for (int il = 0; il < 4; ++il)
                acc += hs[pi*4+il] * A[il*4+q];
            s[pi*4+q] = acc;
        }
    #pragma unroll
    for (int x = 0; x < 16; ++x) s[x] += __shfl_xor(s[x], 1, 64);
    #pragma unroll
    for (int i = 0; i < 4; ++i) {
        float4 v = R4[i];
        s[4*i+0] += v.x; s[4*i+1] += v.y; s[4*i+2] += v.z; s[4*i+3] += v.w;
    }

    // ---- invert S (4x4 SPD), unrolled Gauss-Jordan, no pivoting ----
    float is[16] = {1.f,0.f,0.f,0.f, 0.f,1.f,0.f,0.f, 0.f,0.f,1.f,0.f, 0.f,0.f,0.f,1.f};
    #pragma unroll
    for (int c = 0; c < 4; ++c) {
        float pinv = 1.0f / s[c*4+c];
        #pragma unroll
        for (int k = 0; k < 4; ++k) { s[c*4+k] *= pinv; is[c*4+k] *= pinv; }
        #pragma unroll
        for (int r = 0; r < 4; ++r) {
            if (r != c) {
                float fac = s[r*4+c];
                #pragma unroll
                for (int k = 0; k < 4; ++k) {
                    s[r*4+k]  -= fac * s[c*4+k];
                    is[r*4+k] -= fac * is[c*4+k];
                }
            }
        }
    }

    // ---- KG own rows = A_own @ inv(S), store 4 float4 ----
    float4* out4 = reinterpret_cast<float4*>(out + (size_t)b * 32);
    #pragma unroll
    for (int il = 0; il < 4; ++il) {
        float4 o;
        o.x = A[il*4+0]*is[0] + A[il*4+1]*is[4] + A[il*4+2]*is[8]  + A[il*4+3]*is[12];
        o.y = A[il*4+0]*is[1] + A[il*4+1]*is[5] + A[il*4+2]*is[9]  + A[il*4+3]*is[13];
        o.z = A[il*4+0]*is[2] + A[il*4+1]*is[6] + A[il*4+2]*is[10] + A[il*4+3]*is[14];
        o.w = A[il*4+0]*is[3] + A[il*4+1]*is[7] + A[il*4+2]*is[11] + A[il*4+3]*is[15];
        out4[r0 + il] = o;
    }
}

extern "C" void kernel_launch(void* const* d_in, const int* in_sizes, int n_in,
                              void* d_out, int out_size, void* d_ws, size_t ws_size,
                              hipStream_t stream) {
    const float* F  = (const float*)d_in[0];
    const float* H  = (const float*)d_in[1];
    const float* Sp = (const float*)d_in[2];
    const float* Q  = (const float*)d_in[3];
    const float* R  = (const float*)d_in[4];
    float* out = (float*)d_out;

    int nb = in_sizes[0] / 64;      // B = 262144
    int threads = 256;
    long long total = 2LL * nb;     // two lanes per batch
    int blocks = (int)((total + threads - 1) / threads);
    kalman_gain_kernel<<<blocks, threads, 0, stream>>>(F, H, Sp, Q, R, out, nb);
}

// Round 4
// 54.448 us; speedup vs baseline: 5.5957x; 1.4192x over previous
//
#include <hip/hip_runtime.h>

// KalmanGain: B=262144, N=8, M=4, fp32.
// Round 4: LDS-staged coalesced loads via global_load_lds (width 16).
//   Block = 128 threads (2 waves), 64 batches, 2 lanes/batch.
//   Sigma H^T = F Sp (H F)^T + Q H^T = G u + Q H^T, with G = F Sp.
//   Per lane (p = tid&1 owns rows r0=4p..r0+3):
//     fr = own F rows (LDS), hs = own H column-slice (LDS)
//     u  = (H F)^T partial from own rows, pair-summed via shfl_xor(.,1)
//     G  = own F rows @ Sp (stream Sp rows from LDS)
//     A  = G @ u ; A += Qown @ H^T ; S = H A + R (pair-sum) ; KG = A inv(S)
// LDS granule map (float4 units):
//   F [0,1024) | Sp [1024,2048) | H [2048,2560) | R [2560,2816); Q reuses F.
// Swizzle (rule 21, both-sides): LDS slot (b,j) holds global granule
// k = j ^ (b&mask); reads use granule index j = k ^ (b&mask). Keeps
// global_load_lds dest linear while making stride-256B ds_read_b128
// bank-balanced (8 groups x 8 lanes = floor).
// Q staging is issued right after fr/hs are consumed, overlapping the
// u/G/A compute (async-stage split). 44KB LDS -> 3 blocks/CU.

#define NBB 64
#define THREADS 128

__device__ __forceinline__ void gl_lds16(const float* src, float4* dst) {
    __builtin_amdgcn_global_load_lds(
        (const __attribute__((address_space(1))) unsigned int*)src,
        (__attribute__((address_space(3))) unsigned int*)dst,
        16, 0, 0);
}

__global__ __launch_bounds__(THREADS) void kalman_gain_kernel(
    const float* __restrict__ Fg, const float* __restrict__ Hg,
    const float* __restrict__ Spg, const float* __restrict__ Qg,
    const float* __restrict__ Rg, float* __restrict__ out, int nb)
{
    __shared__ float4 smem4[2816];   // 45056 B

    const int tid  = threadIdx.x;
    const int wid  = tid >> 6;       // wave 0..1
    const int lane = tid & 63;
    const int b0   = blockIdx.x * NBB;

    // ---- phase-1 staging: F, Sp, H, R (issue all, then drain) ----
    for (int r = wid; r < 16; r += 2) {          // F: 16 KB
        int s = (r << 6) | lane;
        int b = s >> 4, j = s & 15, k = j ^ (b & 15);
        gl_lds16(Fg + (size_t)(b0 + b) * 64 + k * 4, smem4 + (r << 6));
    }
    for (int r = wid; r < 16; r += 2) {          // Sp: 16 KB
        int s = (r << 6) | lane;
        int b = s >> 4, j = s & 15, k = j ^ (b & 15);
        gl_lds16(Spg + (size_t)(b0 + b) * 64 + k * 4, smem4 + 1024 + (r << 6));
    }
    for (int r = wid; r < 8; r += 2) {           // H: 8 KB
        int s = (r << 6) | lane;
        int b = s >> 3, j = s & 7, k = j ^ (b & 7);
        gl_lds16(Hg + (size_t)(b0 + b) * 32 + k * 4, smem4 + 2048 + (r << 6));
    }
    for (int r = wid; r < 4; r += 2) {           // R: 4 KB
        int s = (r << 6) | lane;
        int b = s >> 2, j = s & 3, k = j ^ (b & 3);
        gl_lds16(Rg + (size_t)(b0 + b) * 16 + k * 4, smem4 + 2560 + (r << 6));
    }
    asm volatile("s_waitcnt vmcnt(0)" ::: "memory");
    __syncthreads();

    const int b_loc = tid >> 1;      // 0..63
    const int p     = tid & 1;       // own rows 4p..4p+3
    const int bm15  = b_loc & 15;
    const int bm7   = b_loc & 7;

    // ---- hs[j][rl] = H[j][4p+rl] : 4 LDS granules (pair-broadcast) ----
    float hs[16];
    #pragma unroll
    for (int j = 0; j < 4; ++j) {
        float4 v = smem4[2048 + b_loc * 8 + ((2 * j + p) ^ bm7)];
        hs[j*4+0] = v.x; hs[j*4+1] = v.y; hs[j*4+2] = v.z; hs[j*4+3] = v.w;
    }

    // ---- fr = own 4 F rows [4][8] ----
    float fr[32];
    #pragma unroll
    for (int il = 0; il < 4; ++il) {
        #pragma unroll
        for (int hh = 0; hh < 2; ++hh) {
            int k = 8 * p + 2 * il + hh;
            float4 v = smem4[b_loc * 16 + (k ^ bm15)];
            fr[il*8 + hh*4 + 0] = v.x; fr[il*8 + hh*4 + 1] = v.y;
            fr[il*8 + hh*4 + 2] = v.z; fr[il*8 + hh*4 + 3] = v.w;
        }
    }

    // F and H LDS buffers now dead block-wide after this barrier.
    __syncthreads();

    // ---- phase-2 staging: Q -> F's LDS slots (overlaps u/G/A compute) ----
    for (int r = wid; r < 16; r += 2) {
        int s = (r << 6) | lane;
        int b = s >> 4, j = s & 15, k = j ^ (b & 15);
        gl_lds16(Qg + (size_t)(b0 + b) * 64 + k * 4, smem4 + (r << 6));
    }

    // ---- u = (H F)^T [8][4]: own-row partial, then pair-sum ----
    float u[32];
    #pragma unroll
    for (int x = 0; x < 32; ++x) u[x] = 0.f;
    #pragma unroll
    for (int il = 0; il < 4; ++il)
        #pragma unroll
        for (int k = 0; k < 8; ++k)
            #pragma unroll
            for (int j = 0; j < 4; ++j)
                u[k*4+j] += hs[j*4+il] * fr[il*8+k];
    #pragma unroll
    for (int x = 0; x < 32; ++x) u[x] += __shfl_xor(u[x], 1, 64);

    // ---- G = own F rows @ Sp  [4][8] (stream Sp rows from LDS) ----
    float G[32];
    #pragma unroll
    for (int x = 0; x < 32; ++x) G[x] = 0.f;
    #pragma unroll
    for (int k = 0; k < 8; ++k) {
        float4 s0 = smem4[1024 + b_loc * 16 + ((2*k    ) ^ bm15)];
        float4 s1 = smem4[1024 + b_loc * 16 + ((2*k + 1) ^ bm15)];
        float sp[8] = {s0.x,s0.y,s0.z,s0.w, s1.x,s1.y,s1.z,s1.w};
        #pragma unroll
        for (int il = 0; il < 4; ++il)
            #pragma unroll
            for (int c = 0; c < 8; ++c)
                G[il*8+c] += fr[il*8+k] * sp[c];
    }

    // ---- A = G @ u  [4][4] ----
    float A[16];
    #pragma unroll
    for (int il = 0; il < 4; ++il)
        #pragma unroll
        for (int j = 0; j < 4; ++j) {
            float acc = 0.f;
            #pragma unroll
            for (int k = 0; k < 8; ++k)
                acc += G[il*8+k] * u[k*4+j];
            A[il*4+j] = acc;
        }

    // ---- wait for Q staging (all waves), then finish ----
    asm volatile("s_waitcnt vmcnt(0)" ::: "memory");
    __syncthreads();

    // ---- A += Qown @ H^T : qown from LDS(Q), H rows from LDS ----
    float qo[32];
    #pragma unroll
    for (int il = 0; il < 4; ++il) {
        #pragma unroll
        for (int hh = 0; hh < 2; ++hh) {
            int k = 8 * p + 2 * il + hh;
            float4 v = smem4[b_loc * 16 + (k ^ bm15)];
            qo[il*8 + hh*4 + 0] = v.x; qo[il*8 + hh*4 + 1] = v.y;
            qo[il*8 + hh*4 + 2] = v.z; qo[il*8 + hh*4 + 3] = v.w;
        }
    }
    #pragma unroll
    for (int j = 0; j < 4; ++j) {
        float4 h0 = smem4[2048 + b_loc * 8 + ((2*j    ) ^ bm7)];
        float4 h1 = smem4[2048 + b_loc * 8 + ((2*j + 1) ^ bm7)];
        float hrow[8] = {h0.x,h0.y,h0.z,h0.w, h1.x,h1.y,h1.z,h1.w};
        #pragma unroll
        for (int il = 0; il < 4; ++il) {
            float acc = 0.f;
            #pragma unroll
            for (int k = 0; k < 8; ++k)
                acc += qo[il*8+k] * hrow[k];
            A[il*4+j] += acc;
        }
    }

    // ---- S = H A + R : own partial, pair-sum, add R from LDS ----
    float s[16];
    #pragma unroll
    for (int pi = 0; pi < 4; ++pi)
        #pragma unroll
        for (int q = 0; q < 4; ++q) {
            float acc = 0.f;
            #pragma unroll
            for (int il = 0; il < 4; ++il)
                acc += hs[pi*4+il] * A[il*4+q];
            s[pi*4+q] = acc;
        }
    #pragma unroll
    for (int x = 0; x < 16; ++x) s[x] += __shfl_xor(s[x], 1, 64);
    #pragma unroll
    for (int pi = 0; pi < 4; ++pi) {
        float4 v = smem4[2560 + b_loc * 4 + (pi ^ (b_loc & 3))];
        s[pi*4+0] += v.x; s[pi*4+1] += v.y; s[pi*4+2] += v.z; s[pi*4+3] += v.w;
    }

    // ---- invert S (4x4 SPD), unrolled Gauss-Jordan ----
    float is[16] = {1.f,0.f,0.f,0.f, 0.f,1.f,0.f,0.f, 0.f,0.f,1.f,0.f, 0.f,0.f,0.f,1.f};
    #pragma unroll
    for (int c = 0; c < 4; ++c) {
        float pinv = 1.0f / s[c*4+c];
        #pragma unroll
        for (int k = 0; k < 4; ++k) { s[c*4+k] *= pinv; is[c*4+k] *= pinv; }
        #pragma unroll
        for (int r = 0; r < 4; ++r) {
            if (r != c) {
                float fac = s[r*4+c];
                #pragma unroll
                for (int k = 0; k < 4; ++k) {
                    s[r*4+k]  -= fac * s[c*4+k];
                    is[r*4+k] -= fac * is[c*4+k];
                }
            }
        }
    }

    // ---- KG own rows = A @ inv(S), store ----
    float4* outg = reinterpret_cast<float4*>(out) + (size_t)(b0 + b_loc) * 8 + p * 4;
    #pragma unroll
    for (int il = 0; il < 4; ++il) {
        float4 o;
        o.x = A[il*4+0]*is[0] + A[il*4+1]*is[4] + A[il*4+2]*is[8]  + A[il*4+3]*is[12];
        o.y = A[il*4+0]*is[1] + A[il*4+1]*is[5] + A[il*4+2]*is[9]  + A[il*4+3]*is[13];
        o.z = A[il*4+0]*is[2] + A[il*4+1]*is[6] + A[il*4+2]*is[10] + A[il*4+3]*is[14];
        o.w = A[il*4+0]*is[3] + A[il*4+1]*is[7] + A[il*4+2]*is[11] + A[il*4+3]*is[15];
        outg[il] = o;
    }
}

extern "C" void kernel_launch(void* const* d_in, const int* in_sizes, int n_in,
                              void* d_out, int out_size, void* d_ws, size_t ws_size,
                              hipStream_t stream) {
    const float* F  = (const float*)d_in[0];
    const float* H  = (const float*)d_in[1];
    const float* Sp = (const float*)d_in[2];
    const float* Q  = (const float*)d_in[3];
    const float* R  = (const float*)d_in[4];
    float* out = (float*)d_out;

    int nb = in_sizes[0] / 64;          // B = 262144 (divisible by 64)
    int blocks = nb / NBB;              // 4096
    kalman_gain_kernel<<<blocks, THREADS, 0, stream>>>(F, H, Sp, Q, R, out, nb);
}